// Round 8
// baseline (157.578 us; speedup 1.0000x reference)
//
#include <hip/hip_runtime.h>
#include <hip/hip_bf16.h>

// NormalAttention: B=4, N=1600, C=512, heads=8, dh=64. out = softmax(qk^T/8)@k.
// R14: proj critical-path attack. attn is saturated at ~44.5us (R8-R13: all of
// occupancy/traffic/VGPR/load-ratio falsified; R10 structure kept verbatim).
// Timing law: dur = ~92us + attn, where cvt+proj = 46-92us vs ~12us floor --
// proj is latency-bound on its serial 2-barrier staging chain (R12 null
// proved occupancy-insensitivity, like attn). Changes:
//  (a) cvt's x/w bf16 pass FUSED into proj staging (fp32 load -> cvt8 in regs
//      -> ds_write; bit-identical values). cvt shrinks 1906 -> 50 blocks.
//  (b) proj LDS double-buffer: issue kt+1 fp32 loads -> MFMA from buf[cur] ->
//      cvt+write buf[nxt] -> ONE barrier/iter (was 2). Load latency hides
//      under 32 MFMAs. LDS 73.7KB, ep overlays buf0. launch_bounds(256,1).
//  (c) proj tile back to proven 128x128 (R5/R7), epilogue verbatim; k2/kt2
//      chunk layouts untouched. grid (50,8) = 400 blocks, all resident.

typedef __hip_bfloat16 bf16;
typedef __attribute__((ext_vector_type(8))) short short8;
typedef __attribute__((ext_vector_type(4))) short bfx4;
typedef __attribute__((ext_vector_type(4))) float f32x4;

#define NSP 1600
#define CDIM 512
#define DH 64

__device__ __forceinline__ f32x4 mfma32(short8 a, short8 b, f32x4 c) {
  return __builtin_amdgcn_mfma_f32_16x16x32_bf16(a, b, c, 0, 0, 0);
}

#if __has_builtin(__builtin_amdgcn_mfma_f32_16x16x16bf16_1k)
__device__ __forceinline__ f32x4 mfma_k16(bfx4 a, bfx4 b, f32x4 c) {
  return __builtin_amdgcn_mfma_f32_16x16x16bf16_1k(a, b, c, 0, 0, 0);
}
#else
__device__ __forceinline__ f32x4 mfma_k16(bfx4 a, bfx4 b, f32x4 c) {
  short8 a8 = {a.x, a.y, a.z, a.w, 0, 0, 0, 0};
  short8 b8 = {b.x, b.y, b.z, b.w, 0, 0, 0, 0};
  return __builtin_amdgcn_mfma_f32_16x16x32_bf16(a8, b8, c, 0, 0, 0);
}
#endif

__device__ __forceinline__ short8 cvt8(float4 v0, float4 v1) {
  short8 r; bf16* p = (bf16*)&r;
  p[0] = __float2bfloat16(v0.x); p[1] = __float2bfloat16(v0.y);
  p[2] = __float2bfloat16(v0.z); p[3] = __float2bfloat16(v0.w);
  p[4] = __float2bfloat16(v1.x); p[5] = __float2bfloat16(v1.y);
  p[6] = __float2bfloat16(v1.z); p[7] = __float2bfloat16(v1.w);
  return r;
}

// ---------------------------------------------------------------------------
// cvt: sin/cos -> (d,n) fp32 transpose only. 50 blocks. (x/w fused into proj)
// ---------------------------------------------------------------------------
extern "C" __global__ __launch_bounds__(256)
void cvt_kernel(const float* __restrict__ sin_t, const float* __restrict__ cos_t,
                float* __restrict__ sinT, float* __restrict__ cosT)
{
  __shared__ float t_lds[64][68];
  const int t = blockIdx.x, tid = threadIdx.x;
  const float* src = (t < 25) ? sin_t : cos_t;
  float* dst = (t < 25) ? sinT : cosT;
  const int nt = (t < 25) ? t : t - 25;
  const int r = tid >> 2, c = (tid & 3) * 16;
#pragma unroll
  for (int j = 0; j < 4; ++j)
    *(float4*)&t_lds[r][c + j * 4] =
        *(const float4*)(src + (size_t)(nt * 64 + r) * 64 + c + j * 4);
  __syncthreads();
#pragma unroll
  for (int j4 = 0; j4 < 4; ++j4) {
    float4 o;
    o.x = t_lds[c + j4 * 4 + 0][r];
    o.y = t_lds[c + j4 * 4 + 1][r];
    o.z = t_lds[c + j4 * 4 + 2][r];
    o.w = t_lds[c + j4 * 4 + 3][r];
    *(float4*)(dst + (size_t)r * NSP + nt * 64 + c + j4 * 4) = o;
  }
}

// ---------------------------------------------------------------------------
// proj: 128x128 tile, BK=64, grid (50,8). Fused fp32->bf16 staging with LDS
// double-buffer, ONE barrier per kt. Main-loop fragment reads + full epilogue
// = R5/R7 verbatim (k2/kt2 chunk layouts unchanged for the attn reader).
// ---------------------------------------------------------------------------
extern "C" __global__ __launch_bounds__(256, 1)
void proj_kernel(const float* __restrict__ x, const float* __restrict__ w,
                 const float* __restrict__ bias, const float* __restrict__ sinT,
                 const float* __restrict__ cosT, bf16* __restrict__ q_ws,
                 bf16* __restrict__ k2_ws, bf16* __restrict__ kt2_ws)
{
  __shared__ __align__(16) char smem[73728];
  bf16 (*xl0)[72] = (bf16(*)[72])smem;                 // [128][72]
  bf16 (*wl0)[72] = (bf16(*)[72])(smem + 18432);       // [128][72]
  bf16 (*xl1)[72] = (bf16(*)[72])(smem + 36864);
  bf16 (*wl1)[72] = (bf16(*)[72])(smem + 55296);
  bf16* ep = (bf16*)smem;                              // [128][132] overlay

  const int tid  = threadIdx.x;
  const int wave = tid >> 6;
  const int lane = tid & 63;
  const int col  = lane & 15;
  const int quad = lane >> 4;
  const int wm = wave >> 1, wo = wave & 1;
  const int m0 = blockIdx.x * 128;
  const int o0 = blockIdx.y * 128;

  f32x4 acc[4][4];
#pragma unroll
  for (int i = 0; i < 4; ++i)
#pragma unroll
    for (int j = 0; j < 4; ++j) acc[i][j] = {0.f, 0.f, 0.f, 0.f};

  const int srow = tid >> 1;           // 2 threads/row, 32 fp32 cols each
  const int sch  = (tid & 1) * 32;
  const float* xs_base = x + (size_t)(m0 + srow) * CDIM + sch;
  const float* ws_base = w + (size_t)(o0 + srow) * CDIM + sch;

  float4 xr[8], wr[8];
  // prologue: stage kt=0 into buf0
#pragma unroll
  for (int j = 0; j < 8; ++j) xr[j] = *(const float4*)(xs_base + j * 4);
#pragma unroll
  for (int j = 0; j < 8; ++j) wr[j] = *(const float4*)(ws_base + j * 4);
#pragma unroll
  for (int j = 0; j < 4; ++j) {
    *(short8*)&xl0[srow][sch + j * 8] = cvt8(xr[2 * j], xr[2 * j + 1]);
    *(short8*)&wl0[srow][sch + j * 8] = cvt8(wr[2 * j], wr[2 * j + 1]);
  }
  __syncthreads();

#pragma unroll
  for (int kt = 0; kt < 8; ++kt) {
    // issue next tile's global loads (in flight under this tile's MFMAs)
    if (kt < 7) {
#pragma unroll
      for (int j = 0; j < 8; ++j)
        xr[j] = *(const float4*)(xs_base + (kt + 1) * 64 + j * 4);
#pragma unroll
      for (int j = 0; j < 8; ++j)
        wr[j] = *(const float4*)(ws_base + (kt + 1) * 64 + j * 4);
    }
    bf16 (*xl)[72] = (kt & 1) ? xl1 : xl0;
    bf16 (*wl)[72] = (kt & 1) ? wl1 : wl0;
#pragma unroll
    for (int half = 0; half < 2; ++half) {
      short8 af[4], bfr[4];
#pragma unroll
      for (int mt = 0; mt < 4; ++mt)
        af[mt] = *(short8*)&xl[wm * 64 + mt * 16 + col][half * 32 + quad * 8];
#pragma unroll
      for (int ot = 0; ot < 4; ++ot)
        bfr[ot] = *(short8*)&wl[wo * 64 + ot * 16 + col][half * 32 + quad * 8];
#pragma unroll
      for (int mt = 0; mt < 4; ++mt)
#pragma unroll
        for (int ot = 0; ot < 4; ++ot)
          acc[mt][ot] = mfma32(af[mt], bfr[ot], acc[mt][ot]);
    }
    if (kt < 7) {
      bf16 (*xn)[72] = (kt & 1) ? xl0 : xl1;
      bf16 (*wn)[72] = (kt & 1) ? wl0 : wl1;
#pragma unroll
      for (int j = 0; j < 4; ++j) {
        *(short8*)&xn[srow][sch + j * 8] = cvt8(xr[2 * j], xr[2 * j + 1]);
        *(short8*)&wn[srow][sch + j * 8] = cvt8(wr[2 * j], wr[2 * j + 1]);
      }
    }
    __syncthreads();
  }

  // ---- epilogue stage 1: theta_shift -> ep[o_local][m_local] (bf16) ----
  const int b_idx = (m0 + wm * 64) / NSP;
  const int n0w   = m0 + wm * 64 - b_idx * NSP;
  const bool isq  = (o0 < 512);
#pragma unroll
  for (int ot = 0; ot < 4; ++ot) {
    const int o_local = wo * 64 + ot * 16 + col;
    const int o_g = o0 + o_local;
    const float bv = bias[o_g];
    const int d = o_g & 63;
#pragma unroll
    for (int mt = 0; mt < 4; ++mt) {
      const int nl = mt * 16 + quad * 4;
      float t[4], rot[4];
#pragma unroll
      for (int r = 0; r < 4; ++r) t[r] = acc[mt][ot][r] + bv;
#pragma unroll
      for (int r = 0; r < 4; ++r) {
        float tp = __shfl_xor(t[r], 1, 64);
        rot[r] = (lane & 1) ? tp : -tp;
      }
      const float4 c4 = *(const float4*)(cosT + (size_t)d * NSP + n0w + nl);
      const float4 s4 = *(const float4*)(sinT + (size_t)d * NSP + n0w + nl);
      float res[4];
      res[0] = t[0] * c4.x + rot[0] * s4.x;
      res[1] = t[1] * c4.y + rot[1] * s4.y;
      res[2] = t[2] * c4.z + rot[2] * s4.z;
      res[3] = t[3] * c4.w + rot[3] * s4.w;
      if (isq) {
#pragma unroll
        for (int r = 0; r < 4; ++r) res[r] *= 0.125f;
      }
      bfx4 pk; bf16* pp = (bf16*)&pk;
#pragma unroll
      for (int r = 0; r < 4; ++r) pp[r] = __float2bfloat16(res[r]);
      *(bfx4*)&ep[o_local * 132 + wm * 64 + nl] = pk;
    }
  }
  __syncthreads();

  // ---- epilogue stage 2: coalesced global stores (R5/R7 verbatim) ----
  if (isq) {   // q_ws (bh,n,d) natural
    const int m_l = tid >> 1, half = tid & 1;
    const int gm = m0 + m_l;
    const int bi = gm / NSP, n = gm - bi * NSP;
    const int h = (o0 >> 6) + half;
    bf16* base = q_ws + ((size_t)(bi * 8 + h) * NSP + n) * 64;
#pragma unroll
    for (int c = 0; c < 8; ++c) {
      short8 v; bf16* vp = (bf16*)&v;
#pragma unroll
      for (int j = 0; j < 8; ++j) vp[j] = ep[(half * 64 + c * 8 + j) * 132 + m_l];
      *(short8*)(base + c * 8) = v;
    }
  } else {
    const int h0 = (o0 - 512) >> 6;   // 0,2,4,6 ; heads h0, h0+1
    // k2_ws: per (bh,ktile) 512 chunks [kh][ti][f][quad][col];
    // chunk = K[key=(2kh+ti)*16+col][d = (f*4+quad)*8 .. +8]
#pragma unroll
    for (int it = 0; it < 8; ++it) {
      const int ci = it * 256 + tid;              // 0..2047
      const int hh = ci >> 10, T = (ci >> 9) & 1, inner = ci & 511;
      const int ccol = inner & 15, cq = (inner >> 4) & 3;
      const int f = (inner >> 6) & 1, ti = (inner >> 7) & 1, kh2 = (inner >> 8) & 1;
      const int gmb = m0 + T * 64;
      const int bi = gmb / NSP, ktile = (gmb - bi * NSP) >> 6;
      const int m_l = T * 64 + (2 * kh2 + ti) * 16 + ccol;
      const int er0 = hh * 64 + (f * 4 + cq) * 8;
      short8 v; bf16* vp = (bf16*)&v;
#pragma unroll
      for (int j = 0; j < 8; ++j) vp[j] = ep[(er0 + j) * 132 + m_l];
      *(short8*)(k2_ws +
          (((size_t)(bi * 8 + h0 + hh) * 25 + ktile) * 512 + inner) * 8) = v;
    }
    // kt2_ws: per (bh,ktile) 512 chunks [kh][dt][quad][col];
    // chunk = kT[d=dt*16+col][packed keys kh*32+quad*4+{0..3}, +16+{0..3}]
#pragma unroll
    for (int it = 0; it < 8; ++it) {
      const int ci = it * 256 + tid;
      const int hh = ci >> 10, T = (ci >> 9) & 1, inner = ci & 511;
      const int ccol = inner & 15, cq = (inner >> 4) & 3;
      const int dt = (inner >> 6) & 3, kh2 = (inner >> 8) & 1;
      const int gmb = m0 + T * 64;
      const int bi = gmb / NSP, ktile = (gmb - bi * NSP) >> 6;
      const bf16* eprow =
          ep + (hh * 64 + dt * 16 + ccol) * 132 + T * 64 + kh2 * 32 + cq * 4;
      short8 v;
      ((bfx4*)&v)[0] = *(const bfx4*)(eprow);
      ((bfx4*)&v)[1] = *(const bfx4*)(eprow + 16);
      *(short8*)(kt2_ws +
          (((size_t)(bi * 8 + h0 + hh) * 25 + ktile) * 512 + inner) * 8) = v;
    }
  }
}

// ---------------------------------------------------------------------------
// attn: R10 verbatim. LDS-free K-loop (4 waves: qg=wave&1 32 qcols,
// kh=wave>>1 32 keys), XCD-swizzled flat grid (800), register double-buffer,
// launch_bounds(256,2). Best measured: ~44.5us.
// ---------------------------------------------------------------------------

#define LOADF(KF, KTF, KT)                                                    \
  {                                                                           \
    const bf16* kc_  = k2b  + (KT) * 4096;                                    \
    const bf16* kc2_ = kt2b + (KT) * 4096;                                    \
    _Pragma("unroll")                                                         \
    for (int ti = 0; ti < 2; ++ti)                                            \
      _Pragma("unroll")                                                       \
      for (int f = 0; f < 2; ++f)                                             \
        KF[ti][f] =                                                           \
            *(const short8*)(kc_ + (((kh * 2 + ti) * 2 + f) * 64 + lane) * 8);\
    _Pragma("unroll")                                                         \
    for (int dt = 0; dt < 4; ++dt)                                            \
      KTF[dt] = *(const short8*)(kc2_ + ((kh * 4 + dt) * 64 + lane) * 8);     \
  }

#define COMPUTEF(KF, KTF)                                                     \
  {                                                                           \
    f32x4 s[2][2];                                                            \
    _Pragma("unroll")                                                         \
    for (int ti = 0; ti < 2; ++ti)                                            \
      _Pragma("unroll")                                                       \
      for (int ct = 0; ct < 2; ++ct) {                                        \
        f32x4 t = {0.f, 0.f, 0.f, 0.f};                                       \
        t = mfma32(KF[ti][0], qb[ct][0], t);                                  \
        t = mfma32(KF[ti][1], qb[ct][1], t);                                  \
        s[ti][ct] = t;                                                        \
      }                                                                       \
    bfx4 p4[2][2];                                                            \
    _Pragma("unroll")                                                         \
    for (int ti = 0; ti < 2; ++ti)                                            \
      _Pragma("unroll")                                                       \
      for (int ct = 0; ct < 2; ++ct) {                                        \
        _Pragma("unroll")                                                     \
        for (int r = 0; r < 4; ++r) s[ti][ct][r] = __expf(s[ti][ct][r]);      \
        l_part[ct] +=                                                         \
            s[ti][ct][0] + s[ti][ct][1] + s[ti][ct][2] + s[ti][ct][3];        \
        bf16* pp = (bf16*)&p4[ti][ct];                                        \
        _Pragma("unroll")                                                     \
        for (int r = 0; r < 4; ++r) pp[r] = __float2bfloat16(s[ti][ct][r]);   \
      }                                                                       \
    _Pragma("unroll")                                                         \
    for (int dt = 0; dt < 4; ++dt) {                                          \
      bfx4 alo = __builtin_shufflevector(KTF[dt], KTF[dt], 0, 1, 2, 3);       \
      bfx4 ahi = __builtin_shufflevector(KTF[dt], KTF[dt], 4, 5, 6, 7);       \
      _Pragma("unroll")                                                       \
      for (int ct = 0; ct < 2; ++ct) {                                        \
        oacc[dt][ct] = mfma_k16(alo, p4[0][ct], oacc[dt][ct]);                \
        oacc[dt][ct] = mfma_k16(ahi, p4[1][ct], oacc[dt][ct]);                \
      }                                                                       \
    }                                                                         \
  }

extern "C" __global__ __launch_bounds__(256, 2)
void attn_kernel(const bf16* __restrict__ q_ws, const bf16* __restrict__ k2_ws,
                 const bf16* __restrict__ kt2_ws, float* __restrict__ out)
{
  __shared__ float red[2][64][36];

  // XCD swizzle: flat id; id%8 selects XCD (round-robin heuristic) == bh%8,
  // so all 25 qt-blocks of a bh share one XCD's L2. Bijective on 0..799.
  const int id = blockIdx.x;
  const int xr = id & 7, inner = id >> 3;      // inner 0..99
  const int qt = inner % 25;
  const int bh = (inner / 25) * 8 + xr;        // 0..31
  const int b = bh >> 3, h = bh & 7;
  const int tid  = threadIdx.x;
  const int wave = tid >> 6;
  const int lane = tid & 63;
  const int col  = lane & 15;
  const int quad = lane >> 4;
  const int qg = wave & 1, kh = wave >> 1;

  // loop-invariant Q B-fragments (natural layout, one-time strided gather)
  short8 qb[2][2];
#pragma unroll
  for (int ct = 0; ct < 2; ++ct) {
    const bf16* qp =
        q_ws + ((size_t)bh * NSP + qt * 64 + (qg * 2 + ct) * 16 + col) * 64;
    qb[ct][0] = *(const short8*)(qp + quad * 8);
    qb[ct][1] = *(const short8*)(qp + 32 + quad * 8);
  }

  f32x4 oacc[4][2];
#pragma unroll
  for (int i = 0; i < 4; ++i)
#pragma unroll
    for (int j = 0; j < 2; ++j) oacc[i][j] = {0.f, 0.f, 0.f, 0.f};
  float l_part[2] = {0.f, 0.f};

  const bf16* k2b  = k2_ws  + (size_t)bh * 25 * 4096;
  const bf16* kt2b = kt2_ws + (size_t)bh * 25 * 4096;

  // register double-buffer: prefetch kt+1 while computing kt
  short8 kfA[2][2], ktfA[4], kfB[2][2], ktfB[4];
  LOADF(kfA, ktfA, 0)
#pragma unroll 1
  for (int i = 0; i < 12; ++i) {
    LOADF(kfB, ktfB, 2 * i + 1)
    COMPUTEF(kfA, ktfA)
    LOADF(kfA, ktfA, 2 * i + 2)
    COMPUTEF(kfB, ktfB)
  }
  COMPUTEF(kfA, ktfA)

  // reduce l over quads (this wave's 32 keys)
#pragma unroll
  for (int ct = 0; ct < 2; ++ct) {
    l_part[ct] += __shfl_xor(l_part[ct], 16, 64);
    l_part[ct] += __shfl_xor(l_part[ct], 32, 64);
  }

  // cross-wave (kh) reduce via LDS
  if (wave >= 2) {
    float* dst = &red[wave - 2][lane][0];
#pragma unroll
    for (int dt = 0; dt < 4; ++dt)
#pragma unroll
      for (int ct = 0; ct < 2; ++ct)
        *(f32x4*)(dst + (dt * 2 + ct) * 4) = oacc[dt][ct];
    dst[32] = l_part[0]; dst[33] = l_part[1];
  }
  __syncthreads();
  if (wave < 2) {
    const float* srcr = &red[wave][lane][0];
#pragma unroll
    for (int dt = 0; dt < 4; ++dt)
#pragma unroll
      for (int ct = 0; ct < 2; ++ct)
        oacc[dt][ct] += *(const f32x4*)(srcr + (dt * 2 + ct) * 4);
    const float inv0 = 1.f / (l_part[0] + srcr[32]);
    const float inv1 = 1.f / (l_part[1] + srcr[33]);
#pragma unroll
    for (int ct = 0; ct < 2; ++ct) {
      const float inv = ct ? inv1 : inv0;
      const int qrow = qt * 64 + (qg * 2 + ct) * 16 + col;
      float* ob = out + ((size_t)b * NSP + qrow) * CDIM + h * 64;
#pragma unroll
      for (int dt = 0; dt < 4; ++dt) {
        float4 v;
        v.x = oacc[dt][ct][0] * inv; v.y = oacc[dt][ct][1] * inv;
        v.z = oacc[dt][ct][2] * inv; v.w = oacc[dt][ct][3] * inv;
        *(float4*)(ob + dt * 16 + quad * 4) = v;
      }
    }
  }
}

extern "C" void kernel_launch(void* const* d_in, const int* in_sizes, int n_in,
                              void* d_out, int out_size, void* d_ws, size_t ws_size,
                              hipStream_t stream) {
  const float* x     = (const float*)d_in[0];
  const float* sin_t = (const float*)d_in[1];
  const float* cos_t = (const float*)d_in[2];
  const float* w_qkv = (const float*)d_in[3];
  const float* b_qkv = (const float*)d_in[4];
  float* out = (float*)d_out;

  const size_t QK = (size_t)32 * NSP * DH;
  bf16* q_ws   = (bf16*)d_ws;
  bf16* k2_ws  = q_ws + QK;
  bf16* kt2_ws = k2_ws + QK;
  float* sinT  = (float*)(kt2_ws + QK);
  float* cosT  = sinT + (size_t)DH * NSP;

  cvt_kernel<<<50, 256, 0, stream>>>(sin_t, cos_t, sinT, cosT);

  dim3 gproj(50, 8);
  proj_kernel<<<gproj, 256, 0, stream>>>(x, w_qkv, b_qkv, sinT, cosT,
                                         q_ws, k2_ws, kt2_ws);

  attn_kernel<<<800, 256, 0, stream>>>(q_ws, k2_ws, kt2_ws, out);
}

// Round 10
// 151.813 us; speedup vs baseline: 1.0380x; 1.0380x over previous
//
#include <hip/hip_runtime.h>
#include <hip/hip_bf16.h>

// NormalAttention: B=4, N=1600, C=512, heads=8, dh=64. out = softmax(qk^T/8)@k.
// R15 (re-run; previous round was an infra container failure, not a kernel
// verdict). LDS-free proj K-loop. R14 profiled proj: 52.8us at MfmaUtil
// 4.5% -- ~95% staging latency, and every __syncthreads drains vmcnt(0) so
// NO load can stay in flight across the per-kt barriers. Fix: drop LDS
// staging entirely. MFMA fragments are 16B-contiguous in x_bf/w_bf natural
// layout (row*512 + kt*64 + half*32 + quad*8): direct per-lane global loads,
// 4 quads/row = one full 64B line. K-loop has ZERO barriers/LDS; 128 loads +
// 256 MFMAs per block pipeline freely (same LDS-free trick as attn R7/R10).
// Grid flat 400, y=id&7 -> each XCD owns one o-column: x_bf read once per
// XCD from L3 (~105MB total), own 131KB w-panel L2-resident. LDS only for
// the 33.8KB ep epilogue buffer; epilogue + k2/kt2 layouts R5/R7 verbatim.
// cvt: R5 full (fused fp32 staging was R14's regression). attn: R10 verbatim
// (44.5us, saturated after R8-R13 falsifications).

typedef __hip_bfloat16 bf16;
typedef __attribute__((ext_vector_type(8))) short short8;
typedef __attribute__((ext_vector_type(4))) short bfx4;
typedef __attribute__((ext_vector_type(4))) float f32x4;

#define NSP 1600
#define CDIM 512
#define DH 64

__device__ __forceinline__ f32x4 mfma32(short8 a, short8 b, f32x4 c) {
  return __builtin_amdgcn_mfma_f32_16x16x32_bf16(a, b, c, 0, 0, 0);
}

#if __has_builtin(__builtin_amdgcn_mfma_f32_16x16x16bf16_1k)
__device__ __forceinline__ f32x4 mfma_k16(bfx4 a, bfx4 b, f32x4 c) {
  return __builtin_amdgcn_mfma_f32_16x16x16bf16_1k(a, b, c, 0, 0, 0);
}
#else
__device__ __forceinline__ f32x4 mfma_k16(bfx4 a, bfx4 b, f32x4 c) {
  short8 a8 = {a.x, a.y, a.z, a.w, 0, 0, 0, 0};
  short8 b8 = {b.x, b.y, b.z, b.w, 0, 0, 0, 0};
  return __builtin_amdgcn_mfma_f32_16x16x32_bf16(a8, b8, c, 0, 0, 0);
}
#endif

__device__ __forceinline__ short8 cvt8(float4 v0, float4 v1) {
  short8 r; bf16* p = (bf16*)&r;
  p[0] = __float2bfloat16(v0.x); p[1] = __float2bfloat16(v0.y);
  p[2] = __float2bfloat16(v0.z); p[3] = __float2bfloat16(v0.w);
  p[4] = __float2bfloat16(v1.x); p[5] = __float2bfloat16(v1.y);
  p[6] = __float2bfloat16(v1.z); p[7] = __float2bfloat16(v1.w);
  return r;
}

// ---------------------------------------------------------------------------
// cvt: x,w -> bf16 (plain); sin/cos -> (d,n) fp32 transpose.  (R5 verbatim)
// ---------------------------------------------------------------------------
extern "C" __global__ __launch_bounds__(256)
void cvt_kernel(const float* __restrict__ x, const float* __restrict__ w,
                const float* __restrict__ sin_t, const float* __restrict__ cos_t,
                bf16* __restrict__ x_bf, bf16* __restrict__ w_bf,
                float* __restrict__ sinT, float* __restrict__ cosT)
{
  __shared__ float t_lds[64][68];
  const int bid = blockIdx.x, tid = threadIdx.x;
  if (bid < 1600) {
    const size_t i = (size_t)bid * 2048 + tid * 8;
    float4 v0 = *(const float4*)(x + i);
    float4 v1 = *(const float4*)(x + i + 4);
    *(short8*)(x_bf + i) = cvt8(v0, v1);
  } else if (bid < 1856) {
    const size_t i = (size_t)(bid - 1600) * 2048 + tid * 8;
    float4 v0 = *(const float4*)(w + i);
    float4 v1 = *(const float4*)(w + i + 4);
    *(short8*)(w_bf + i) = cvt8(v0, v1);
  } else {
    const int t = bid - 1856;
    const float* src = (t < 25) ? sin_t : cos_t;
    float* dst = (t < 25) ? sinT : cosT;
    const int nt = (t < 25) ? t : t - 25;
    const int r = tid >> 2, c = (tid & 3) * 16;
#pragma unroll
    for (int j = 0; j < 4; ++j)
      *(float4*)&t_lds[r][c + j * 4] =
          *(const float4*)(src + (size_t)(nt * 64 + r) * 64 + c + j * 4);
    __syncthreads();
#pragma unroll
    for (int j4 = 0; j4 < 4; ++j4) {
      float4 o;
      o.x = t_lds[c + j4 * 4 + 0][r];
      o.y = t_lds[c + j4 * 4 + 1][r];
      o.z = t_lds[c + j4 * 4 + 2][r];
      o.w = t_lds[c + j4 * 4 + 3][r];
      *(float4*)(dst + (size_t)r * NSP + nt * 64 + c + j4 * 4) = o;
    }
  }
}

// ---------------------------------------------------------------------------
// proj: 128x128 tile, BK=64, flat grid 400 (m=id>>3, o=id&7 -> one o-column
// per XCD). LDS-FREE barrier-free K-loop: direct per-lane fragment loads from
// x_bf/w_bf. LDS only for ep epilogue buffer. Epilogue R5/R7 verbatim.
// ---------------------------------------------------------------------------
extern "C" __global__ __launch_bounds__(256, 1)
void proj_kernel(const bf16* __restrict__ x_bf, const bf16* __restrict__ w_bf,
                 const float* __restrict__ bias, const float* __restrict__ sinT,
                 const float* __restrict__ cosT, bf16* __restrict__ q_ws,
                 bf16* __restrict__ k2_ws, bf16* __restrict__ kt2_ws)
{
  __shared__ __align__(16) char smem[33792];
  bf16* ep = (bf16*)smem;                              // [128][132]

  const int tid  = threadIdx.x;
  const int wave = tid >> 6;
  const int lane = tid & 63;
  const int col  = lane & 15;
  const int quad = lane >> 4;
  const int wm = wave >> 1, wo = wave & 1;
  const int id = blockIdx.x;
  const int m0 = (id >> 3) * 128;
  const int o0 = (id & 7) * 128;

  f32x4 acc[4][4];
#pragma unroll
  for (int i = 0; i < 4; ++i)
#pragma unroll
    for (int j = 0; j < 4; ++j) acc[i][j] = {0.f, 0.f, 0.f, 0.f};

  // per-lane fragment bases: row = base + mt*16 (x) / ot*16 (w), 16B chunk at
  // kt*64 + half*32 + quad*8. Each (mt,half): 16 rows x 64B lines, fully used.
  const bf16* xb = x_bf + ((size_t)(m0 + wm * 64 + col) << 9) + quad * 8;
  const bf16* wb = w_bf + ((size_t)(o0 + wo * 64 + col) << 9) + quad * 8;

#pragma unroll
  for (int kt = 0; kt < 8; ++kt) {
#pragma unroll
    for (int half = 0; half < 2; ++half) {
      const int c0 = kt * 64 + half * 32;
      short8 af[4], bfr[4];
#pragma unroll
      for (int mt = 0; mt < 4; ++mt)
        af[mt] = *(const short8*)(xb + ((size_t)mt << 13) + c0);
#pragma unroll
      for (int ot = 0; ot < 4; ++ot)
        bfr[ot] = *(const short8*)(wb + ((size_t)ot << 13) + c0);
#pragma unroll
      for (int mt = 0; mt < 4; ++mt)
#pragma unroll
        for (int ot = 0; ot < 4; ++ot)
          acc[mt][ot] = mfma32(af[mt], bfr[ot], acc[mt][ot]);
    }
  }

  // ---- epilogue stage 1: theta_shift -> ep[o_local][m_local] (bf16) ----
  const int b_idx = (m0 + wm * 64) / NSP;
  const int n0w   = m0 + wm * 64 - b_idx * NSP;
  const bool isq  = (o0 < 512);
#pragma unroll
  for (int ot = 0; ot < 4; ++ot) {
    const int o_local = wo * 64 + ot * 16 + col;
    const int o_g = o0 + o_local;
    const float bv = bias[o_g];
    const int d = o_g & 63;
#pragma unroll
    for (int mt = 0; mt < 4; ++mt) {
      const int nl = mt * 16 + quad * 4;
      float t[4], rot[4];
#pragma unroll
      for (int r = 0; r < 4; ++r) t[r] = acc[mt][ot][r] + bv;
#pragma unroll
      for (int r = 0; r < 4; ++r) {
        float tp = __shfl_xor(t[r], 1, 64);
        rot[r] = (lane & 1) ? tp : -tp;
      }
      const float4 c4 = *(const float4*)(cosT + (size_t)d * NSP + n0w + nl);
      const float4 s4 = *(const float4*)(sinT + (size_t)d * NSP + n0w + nl);
      float res[4];
      res[0] = t[0] * c4.x + rot[0] * s4.x;
      res[1] = t[1] * c4.y + rot[1] * s4.y;
      res[2] = t[2] * c4.z + rot[2] * s4.z;
      res[3] = t[3] * c4.w + rot[3] * s4.w;
      if (isq) {
#pragma unroll
        for (int r = 0; r < 4; ++r) res[r] *= 0.125f;
      }
      bfx4 pk; bf16* pp = (bf16*)&pk;
#pragma unroll
      for (int r = 0; r < 4; ++r) pp[r] = __float2bfloat16(res[r]);
      *(bfx4*)&ep[o_local * 132 + wm * 64 + nl] = pk;
    }
  }
  __syncthreads();

  // ---- epilogue stage 2: coalesced global stores (R5/R7 verbatim) ----
  if (isq) {   // q_ws (bh,n,d) natural
    const int m_l = tid >> 1, half = tid & 1;
    const int gm = m0 + m_l;
    const int bi = gm / NSP, n = gm - bi * NSP;
    const int h = (o0 >> 6) + half;
    bf16* base = q_ws + ((size_t)(bi * 8 + h) * NSP + n) * 64;
#pragma unroll
    for (int c = 0; c < 8; ++c) {
      short8 v; bf16* vp = (bf16*)&v;
#pragma unroll
      for (int j = 0; j < 8; ++j) vp[j] = ep[(half * 64 + c * 8 + j) * 132 + m_l];
      *(short8*)(base + c * 8) = v;
    }
  } else {
    const int h0 = (o0 - 512) >> 6;   // 0,2,4,6 ; heads h0, h0+1
    // k2_ws: per (bh,ktile) 512 chunks [kh][ti][f][quad][col];
    // chunk = K[key=(2kh+ti)*16+col][d = (f*4+quad)*8 .. +8]
#pragma unroll
    for (int it = 0; it < 8; ++it) {
      const int ci = it * 256 + tid;              // 0..2047
      const int hh = ci >> 10, T = (ci >> 9) & 1, inner = ci & 511;
      const int ccol = inner & 15, cq = (inner >> 4) & 3;
      const int f = (inner >> 6) & 1, ti = (inner >> 7) & 1, kh2 = (inner >> 8) & 1;
      const int gmb = m0 + T * 64;
      const int bi = gmb / NSP, ktile = (gmb - bi * NSP) >> 6;
      const int m_l = T * 64 + (2 * kh2 + ti) * 16 + ccol;
      const int er0 = hh * 64 + (f * 4 + cq) * 8;
      short8 v; bf16* vp = (bf16*)&v;
#pragma unroll
      for (int j = 0; j < 8; ++j) vp[j] = ep[(er0 + j) * 132 + m_l];
      *(short8*)(k2_ws +
          (((size_t)(bi * 8 + h0 + hh) * 25 + ktile) * 512 + inner) * 8) = v;
    }
    // kt2_ws: per (bh,ktile) 512 chunks [kh][dt][quad][col];
    // chunk = kT[d=dt*16+col][packed keys kh*32+quad*4+{0..3}, +16+{0..3}]
#pragma unroll
    for (int it = 0; it < 8; ++it) {
      const int ci = it * 256 + tid;
      const int hh = ci >> 10, T = (ci >> 9) & 1, inner = ci & 511;
      const int ccol = inner & 15, cq = (inner >> 4) & 3;
      const int dt = (inner >> 6) & 3, kh2 = (inner >> 8) & 1;
      const int gmb = m0 + T * 64;
      const int bi = gmb / NSP, ktile = (gmb - bi * NSP) >> 6;
      const bf16* eprow =
          ep + (hh * 64 + dt * 16 + ccol) * 132 + T * 64 + kh2 * 32 + cq * 4;
      short8 v;
      ((bfx4*)&v)[0] = *(const bfx4*)(eprow);
      ((bfx4*)&v)[1] = *(const bfx4*)(eprow + 16);
      *(short8*)(kt2_ws +
          (((size_t)(bi * 8 + h0 + hh) * 25 + ktile) * 512 + inner) * 8) = v;
    }
  }
}

// ---------------------------------------------------------------------------
// attn: R10 verbatim. LDS-free K-loop (4 waves: qg=wave&1 32 qcols,
// kh=wave>>1 32 keys), XCD-swizzled flat grid (800), register double-buffer,
// launch_bounds(256,2). Best measured: ~44.5us.
// ---------------------------------------------------------------------------

#define LOADF(KF, KTF, KT)                                                    \
  {                                                                           \
    const bf16* kc_  = k2b  + (KT) * 4096;                                    \
    const bf16* kc2_ = kt2b + (KT) * 4096;                                    \
    _Pragma("unroll")                                                         \
    for (int ti = 0; ti < 2; ++ti)                                            \
      _Pragma("unroll")                                                       \
      for (int f = 0; f < 2; ++f)                                             \
        KF[ti][f] =                                                           \
            *(const short8*)(kc_ + (((kh * 2 + ti) * 2 + f) * 64 + lane) * 8);\
    _Pragma("unroll")                                                         \
    for (int dt = 0; dt < 4; ++dt)                                            \
      KTF[dt] = *(const short8*)(kc2_ + ((kh * 4 + dt) * 64 + lane) * 8);     \
  }

#define COMPUTEF(KF, KTF)                                                     \
  {                                                                           \
    f32x4 s[2][2];                                                            \
    _Pragma("unroll")                                                         \
    for (int ti = 0; ti < 2; ++ti)                                            \
      _Pragma("unroll")                                                       \
      for (int ct = 0; ct < 2; ++ct) {                                        \
        f32x4 t = {0.f, 0.f, 0.f, 0.f};                                       \
        t = mfma32(KF[ti][0], qb[ct][0], t);                                  \
        t = mfma32(KF[ti][1], qb[ct][1], t);                                  \
        s[ti][ct] = t;                                                        \
      }                                                                       \
    bfx4 p4[2][2];                                                            \
    _Pragma("unroll")                                                         \
    for (int ti = 0; ti < 2; ++ti)                                            \
      _Pragma("unroll")                                                       \
      for (int ct = 0; ct < 2; ++ct) {                                        \
        _Pragma("unroll")                                                     \
        for (int r = 0; r < 4; ++r) s[ti][ct][r] = __expf(s[ti][ct][r]);      \
        l_part[ct] +=                                                         \
            s[ti][ct][0] + s[ti][ct][1] + s[ti][ct][2] + s[ti][ct][3];        \
        bf16* pp = (bf16*)&p4[ti][ct];                                        \
        _Pragma("unroll")                                                     \
        for (int r = 0; r < 4; ++r) pp[r] = __float2bfloat16(s[ti][ct][r]);   \
      }                                                                       \
    _Pragma("unroll")                                                         \
    for (int dt = 0; dt < 4; ++dt) {                                          \
      bfx4 alo = __builtin_shufflevector(KTF[dt], KTF[dt], 0, 1, 2, 3);       \
      bfx4 ahi = __builtin_shufflevector(KTF[dt], KTF[dt], 4, 5, 6, 7);       \
      _Pragma("unroll")                                                       \
      for (int ct = 0; ct < 2; ++ct) {                                        \
        oacc[dt][ct] = mfma_k16(alo, p4[0][ct], oacc[dt][ct]);                \
        oacc[dt][ct] = mfma_k16(ahi, p4[1][ct], oacc[dt][ct]);                \
      }                                                                       \
    }                                                                         \
  }

extern "C" __global__ __launch_bounds__(256, 2)
void attn_kernel(const bf16* __restrict__ q_ws, const bf16* __restrict__ k2_ws,
                 const bf16* __restrict__ kt2_ws, float* __restrict__ out)
{
  __shared__ float red[2][64][36];

  // XCD swizzle: flat id; id%8 selects XCD (round-robin heuristic) == bh%8,
  // so all 25 qt-blocks of a bh share one XCD's L2. Bijective on 0..799.
  const int id = blockIdx.x;
  const int xr = id & 7, inner = id >> 3;      // inner 0..99
  const int qt = inner % 25;
  const int bh = (inner / 25) * 8 + xr;        // 0..31
  const int b = bh >> 3, h = bh & 7;
  const int tid  = threadIdx.x;
  const int wave = tid >> 6;
  const int lane = tid & 63;
  const int col  = lane & 15;
  const int quad = lane >> 4;
  const int qg = wave & 1, kh = wave >> 1;

  // loop-invariant Q B-fragments (natural layout, one-time strided gather)
  short8 qb[2][2];
#pragma unroll
  for (int ct = 0; ct < 2; ++ct) {
    const bf16* qp =
        q_ws + ((size_t)bh * NSP + qt * 64 + (qg * 2 + ct) * 16 + col) * 64;
    qb[ct][0] = *(const short8*)(qp + quad * 8);
    qb[ct][1] = *(const short8*)(qp + 32 + quad * 8);
  }

  f32x4 oacc[4][2];
#pragma unroll
  for (int i = 0; i < 4; ++i)
#pragma unroll
    for (int j = 0; j < 2; ++j) oacc[i][j] = {0.f, 0.f, 0.f, 0.f};
  float l_part[2] = {0.f, 0.f};

  const bf16* k2b  = k2_ws  + (size_t)bh * 25 * 4096;
  const bf16* kt2b = kt2_ws + (size_t)bh * 25 * 4096;

  // register double-buffer: prefetch kt+1 while computing kt
  short8 kfA[2][2], ktfA[4], kfB[2][2], ktfB[4];
  LOADF(kfA, ktfA, 0)
#pragma unroll 1
  for (int i = 0; i < 12; ++i) {
    LOADF(kfB, ktfB, 2 * i + 1)
    COMPUTEF(kfA, ktfA)
    LOADF(kfA, ktfA, 2 * i + 2)
    COMPUTEF(kfB, ktfB)
  }
  COMPUTEF(kfA, ktfA)

  // reduce l over quads (this wave's 32 keys)
#pragma unroll
  for (int ct = 0; ct < 2; ++ct) {
    l_part[ct] += __shfl_xor(l_part[ct], 16, 64);
    l_part[ct] += __shfl_xor(l_part[ct], 32, 64);
  }

  // cross-wave (kh) reduce via LDS
  if (wave >= 2) {
    float* dst = &red[wave - 2][lane][0];
#pragma unroll
    for (int dt = 0; dt < 4; ++dt)
#pragma unroll
      for (int ct = 0; ct < 2; ++ct)
        *(f32x4*)(dst + (dt * 2 + ct) * 4) = oacc[dt][ct];
    dst[32] = l_part[0]; dst[33] = l_part[1];
  }
  __syncthreads();
  if (wave < 2) {
    const float* srcr = &red[wave][lane][0];
#pragma unroll
    for (int dt = 0; dt < 4; ++dt)
#pragma unroll
      for (int ct = 0; ct < 2; ++ct)
        oacc[dt][ct] += *(const f32x4*)(srcr + (dt * 2 + ct) * 4);
    const float inv0 = 1.f / (l_part[0] + srcr[32]);
    const float inv1 = 1.f / (l_part[1] + srcr[33]);
#pragma unroll
    for (int ct = 0; ct < 2; ++ct) {
      const float inv = ct ? inv1 : inv0;
      const int qrow = qt * 64 + (qg * 2 + ct) * 16 + col;
      float* ob = out + ((size_t)b * NSP + qrow) * CDIM + h * 64;
#pragma unroll
      for (int dt = 0; dt < 4; ++dt) {
        float4 v;
        v.x = oacc[dt][ct][0] * inv; v.y = oacc[dt][ct][1] * inv;
        v.z = oacc[dt][ct][2] * inv; v.w = oacc[dt][ct][3] * inv;
        *(float4*)(ob + dt * 16 + quad * 4) = v;
      }
    }
  }
}

extern "C" void kernel_launch(void* const* d_in, const int* in_sizes, int n_in,
                              void* d_out, int out_size, void* d_ws, size_t ws_size,
                              hipStream_t stream) {
  const float* x     = (const float*)d_in[0];
  const float* sin_t = (const float*)d_in[1];
  const float* cos_t = (const float*)d_in[2];
  const float* w_qkv = (const float*)d_in[3];
  const float* b_qkv = (const float*)d_in[4];
  float* out = (float*)d_out;

  const size_t QK = (size_t)32 * NSP * DH;
  bf16* q_ws   = (bf16*)d_ws;
  bf16* k2_ws  = q_ws + QK;
  bf16* kt2_ws = k2_ws + QK;
  bf16* x_bf   = kt2_ws + QK;
  bf16* w_bf   = x_bf + (size_t)6400 * CDIM;
  float* sinT  = (float*)(w_bf + (size_t)1024 * CDIM);
  float* cosT  = sinT + (size_t)DH * NSP;

  cvt_kernel<<<1906, 256, 0, stream>>>(x, w_qkv, sin_t, cos_t, x_bf, w_bf, sinT, cosT);

  proj_kernel<<<400, 256, 0, stream>>>(x_bf, w_bf, b_qkv, sinT, cosT,
                                       q_ws, k2_ws, kt2_ws);

  attn_kernel<<<800, 256, 0, stream>>>(q_ws, k2_ws, kt2_ws, out);
}

// Round 11
// 133.837 us; speedup vs baseline: 1.1774x; 1.1343x over previous
//
#include <hip/hip_runtime.h>
#include <hip/hip_bf16.h>

// NormalAttention: B=4, N=1600, C=512, heads=8, dh=64. out = softmax(qk^T/8)@k.
// R16: revert to R4-best config (total 136.7: cvt R5 + proj R5 staged + attn
// R10), then swap proj's staging to global_load_lds width=16 (m97 pattern,
// documented +67% on this exact staging-bound 128^2 structure). R15's
// LDS-free proj regressed (+15us): no LDS reuse, 8-deep L2 load chain didn't
// pipeline. global_load_lds writes linearly -> LDS [128][64] UNPADDED with
// XOR swizzle done on BOTH sides: source addr pre-swizzled per lane
// (chunk ^ (row&7), involution) and ds_read offset XORed identically, so
// fragment values are bit-identical to R5's padded version (2-way bank
// conflicts on read = free). Epilogue + k2/kt2 layouts R5/R7 verbatim.
// attn: R10 verbatim (44.5us, saturated). cvt: R5 verbatim.

typedef __hip_bfloat16 bf16;
typedef __attribute__((ext_vector_type(8))) short short8;
typedef __attribute__((ext_vector_type(4))) short bfx4;
typedef __attribute__((ext_vector_type(4))) float f32x4;

#define NSP 1600
#define CDIM 512
#define DH 64

#define GLD16(g, l)                                                           \
  __builtin_amdgcn_global_load_lds(                                           \
      (const __attribute__((address_space(1))) unsigned int*)(g),             \
      (__attribute__((address_space(3))) unsigned int*)(l), 16, 0, 0)

__device__ __forceinline__ f32x4 mfma32(short8 a, short8 b, f32x4 c) {
  return __builtin_amdgcn_mfma_f32_16x16x32_bf16(a, b, c, 0, 0, 0);
}

#if __has_builtin(__builtin_amdgcn_mfma_f32_16x16x16bf16_1k)
__device__ __forceinline__ f32x4 mfma_k16(bfx4 a, bfx4 b, f32x4 c) {
  return __builtin_amdgcn_mfma_f32_16x16x16bf16_1k(a, b, c, 0, 0, 0);
}
#else
__device__ __forceinline__ f32x4 mfma_k16(bfx4 a, bfx4 b, f32x4 c) {
  short8 a8 = {a.x, a.y, a.z, a.w, 0, 0, 0, 0};
  short8 b8 = {b.x, b.y, b.z, b.w, 0, 0, 0, 0};
  return __builtin_amdgcn_mfma_f32_16x16x32_bf16(a8, b8, c, 0, 0, 0);
}
#endif

__device__ __forceinline__ short8 cvt8(float4 v0, float4 v1) {
  short8 r; bf16* p = (bf16*)&r;
  p[0] = __float2bfloat16(v0.x); p[1] = __float2bfloat16(v0.y);
  p[2] = __float2bfloat16(v0.z); p[3] = __float2bfloat16(v0.w);
  p[4] = __float2bfloat16(v1.x); p[5] = __float2bfloat16(v1.y);
  p[6] = __float2bfloat16(v1.z); p[7] = __float2bfloat16(v1.w);
  return r;
}

// ---------------------------------------------------------------------------
// cvt: x,w -> bf16 (plain); sin/cos -> (d,n) fp32 transpose.  (R5 verbatim)
// ---------------------------------------------------------------------------
extern "C" __global__ __launch_bounds__(256)
void cvt_kernel(const float* __restrict__ x, const float* __restrict__ w,
                const float* __restrict__ sin_t, const float* __restrict__ cos_t,
                bf16* __restrict__ x_bf, bf16* __restrict__ w_bf,
                float* __restrict__ sinT, float* __restrict__ cosT)
{
  __shared__ float t_lds[64][68];
  const int bid = blockIdx.x, tid = threadIdx.x;
  if (bid < 1600) {
    const size_t i = (size_t)bid * 2048 + tid * 8;
    float4 v0 = *(const float4*)(x + i);
    float4 v1 = *(const float4*)(x + i + 4);
    *(short8*)(x_bf + i) = cvt8(v0, v1);
  } else if (bid < 1856) {
    const size_t i = (size_t)(bid - 1600) * 2048 + tid * 8;
    float4 v0 = *(const float4*)(w + i);
    float4 v1 = *(const float4*)(w + i + 4);
    *(short8*)(w_bf + i) = cvt8(v0, v1);
  } else {
    const int t = bid - 1856;
    const float* src = (t < 25) ? sin_t : cos_t;
    float* dst = (t < 25) ? sinT : cosT;
    const int nt = (t < 25) ? t : t - 25;
    const int r = tid >> 2, c = (tid & 3) * 16;
#pragma unroll
    for (int j = 0; j < 4; ++j)
      *(float4*)&t_lds[r][c + j * 4] =
          *(const float4*)(src + (size_t)(nt * 64 + r) * 64 + c + j * 4);
    __syncthreads();
#pragma unroll
    for (int j4 = 0; j4 < 4; ++j4) {
      float4 o;
      o.x = t_lds[c + j4 * 4 + 0][r];
      o.y = t_lds[c + j4 * 4 + 1][r];
      o.z = t_lds[c + j4 * 4 + 2][r];
      o.w = t_lds[c + j4 * 4 + 3][r];
      *(float4*)(dst + (size_t)r * NSP + nt * 64 + c + j4 * 4) = o;
    }
  }
}

// ---------------------------------------------------------------------------
// proj: 128x128 tile, BK=64, grid (50,8). Staging via global_load_lds w=16:
// LDS [128][64] linear; lane l of instr i (wave sw) writes chunk (l&7) of
// row sw*32+i*8+(l>>3); source chunk pre-swizzled (l&7)^(l>>3). Fragment
// ds_read applies the same XOR: chunk' = (half*4+quad) ^ (col&7). Values
// delivered to MFMA are bit-identical to R5's padded staging. One stage +
// 2 barriers per kt (m97 structure). Epilogue R5/R7 verbatim.
// ---------------------------------------------------------------------------
extern "C" __global__ __launch_bounds__(256)
void proj_kernel(const bf16* __restrict__ x_bf, const bf16* __restrict__ w_bf,
                 const float* __restrict__ bias, const float* __restrict__ sinT,
                 const float* __restrict__ cosT, bf16* __restrict__ q_ws,
                 bf16* __restrict__ k2_ws, bf16* __restrict__ kt2_ws)
{
  __shared__ __align__(16) char smem[33792];
  char* xls = smem;              // [128][64] bf16 = 16384 B
  char* wls = smem + 16384;      // [128][64] bf16 = 16384 B
  bf16* ep = (bf16*)smem;        // [128][132] epilogue overlay (33792 B)

  const int tid  = threadIdx.x;
  const int wave = tid >> 6;
  const int lane = tid & 63;
  const int col  = lane & 15;
  const int quad = lane >> 4;
  const int wm = wave >> 1, wo = wave & 1;
  const int m0 = blockIdx.x * 128;
  const int o0 = blockIdx.y * 128;

  f32x4 acc[4][4];
#pragma unroll
  for (int i = 0; i < 4; ++i)
#pragma unroll
    for (int j = 0; j < 4; ++j) acc[i][j] = {0.f, 0.f, 0.f, 0.f};

  // staging geometry: per wave 4 instrs x (x,w); instr i covers rows
  // wave*32 + i*8 .. +7. lane l -> row_l = l>>3, chunk = l&7.
  const int rl = lane >> 3;            // 0..7
  const int ck = lane & 7;             // 0..7
  const int sck = ck ^ rl;             // pre-swizzled source chunk
  const int c7 = col & 7;              // read-side XOR key

  for (int kt = 0; kt < 8; ++kt) {
#pragma unroll
    for (int i = 0; i < 4; ++i) {
      const int row = wave * 32 + i * 8 + rl;
      const bf16* gx = x_bf + ((size_t)(m0 + row) << 9) + kt * 64 + sck * 8;
      const bf16* gw = w_bf + ((size_t)(o0 + row) << 9) + kt * 64 + sck * 8;
      GLD16(gx, xls + wave * 4096 + i * 1024);
      GLD16(gw, wls + wave * 4096 + i * 1024);
    }
    __syncthreads();   // drains vmcnt(0): staged data visible
#pragma unroll
    for (int half = 0; half < 2; ++half) {
      short8 af[4], bfr[4];
#pragma unroll
      for (int mt = 0; mt < 4; ++mt) {
        const int r = wm * 64 + mt * 16 + col;
        af[mt] = *(const short8*)(xls + r * 128 + (((half * 4 + quad) ^ c7) << 4));
      }
#pragma unroll
      for (int ot = 0; ot < 4; ++ot) {
        const int r = wo * 64 + ot * 16 + col;
        bfr[ot] = *(const short8*)(wls + r * 128 + (((half * 4 + quad) ^ c7) << 4));
      }
#pragma unroll
      for (int mt = 0; mt < 4; ++mt)
#pragma unroll
        for (int ot = 0; ot < 4; ++ot)
          acc[mt][ot] = mfma32(af[mt], bfr[ot], acc[mt][ot]);
    }
    __syncthreads();   // protect LDS before next stage / epilogue overlay
  }

  // ---- epilogue stage 1: theta_shift -> ep[o_local][m_local] (bf16) ----
  const int b_idx = (m0 + wm * 64) / NSP;
  const int n0w   = m0 + wm * 64 - b_idx * NSP;
  const bool isq  = (o0 < 512);
#pragma unroll
  for (int ot = 0; ot < 4; ++ot) {
    const int o_local = wo * 64 + ot * 16 + col;
    const int o_g = o0 + o_local;
    const float bv = bias[o_g];
    const int d = o_g & 63;
#pragma unroll
    for (int mt = 0; mt < 4; ++mt) {
      const int nl = mt * 16 + quad * 4;
      float t[4], rot[4];
#pragma unroll
      for (int r = 0; r < 4; ++r) t[r] = acc[mt][ot][r] + bv;
#pragma unroll
      for (int r = 0; r < 4; ++r) {
        float tp = __shfl_xor(t[r], 1, 64);
        rot[r] = (lane & 1) ? tp : -tp;
      }
      const float4 c4 = *(const float4*)(cosT + (size_t)d * NSP + n0w + nl);
      const float4 s4 = *(const float4*)(sinT + (size_t)d * NSP + n0w + nl);
      float res[4];
      res[0] = t[0] * c4.x + rot[0] * s4.x;
      res[1] = t[1] * c4.y + rot[1] * s4.y;
      res[2] = t[2] * c4.z + rot[2] * s4.z;
      res[3] = t[3] * c4.w + rot[3] * s4.w;
      if (isq) {
#pragma unroll
        for (int r = 0; r < 4; ++r) res[r] *= 0.125f;
      }
      bfx4 pk; bf16* pp = (bf16*)&pk;
#pragma unroll
      for (int r = 0; r < 4; ++r) pp[r] = __float2bfloat16(res[r]);
      *(bfx4*)&ep[o_local * 132 + wm * 64 + nl] = pk;
    }
  }
  __syncthreads();

  // ---- epilogue stage 2: coalesced global stores (R5/R7 verbatim) ----
  if (isq) {   // q_ws (bh,n,d) natural
    const int m_l = tid >> 1, half = tid & 1;
    const int gm = m0 + m_l;
    const int bi = gm / NSP, n = gm - bi * NSP;
    const int h = (o0 >> 6) + half;
    bf16* base = q_ws + ((size_t)(bi * 8 + h) * NSP + n) * 64;
#pragma unroll
    for (int c = 0; c < 8; ++c) {
      short8 v; bf16* vp = (bf16*)&v;
#pragma unroll
      for (int j = 0; j < 8; ++j) vp[j] = ep[(half * 64 + c * 8 + j) * 132 + m_l];
      *(short8*)(base + c * 8) = v;
    }
  } else {
    const int h0 = (o0 - 512) >> 6;   // 0,2,4,6 ; heads h0, h0+1
    // k2_ws: per (bh,ktile) 512 chunks [kh][ti][f][quad][col];
    // chunk = K[key=(2kh+ti)*16+col][d = (f*4+quad)*8 .. +8]
#pragma unroll
    for (int it = 0; it < 8; ++it) {
      const int ci = it * 256 + tid;              // 0..2047
      const int hh = ci >> 10, T = (ci >> 9) & 1, inner = ci & 511;
      const int ccol = inner & 15, cq = (inner >> 4) & 3;
      const int f = (inner >> 6) & 1, ti = (inner >> 7) & 1, kh2 = (inner >> 8) & 1;
      const int gmb = m0 + T * 64;
      const int bi = gmb / NSP, ktile = (gmb - bi * NSP) >> 6;
      const int m_l = T * 64 + (2 * kh2 + ti) * 16 + ccol;
      const int er0 = hh * 64 + (f * 4 + cq) * 8;
      short8 v; bf16* vp = (bf16*)&v;
#pragma unroll
      for (int j = 0; j < 8; ++j) vp[j] = ep[(er0 + j) * 132 + m_l];
      *(short8*)(k2_ws +
          (((size_t)(bi * 8 + h0 + hh) * 25 + ktile) * 512 + inner) * 8) = v;
    }
    // kt2_ws: per (bh,ktile) 512 chunks [kh][dt][quad][col];
    // chunk = kT[d=dt*16+col][packed keys kh*32+quad*4+{0..3}, +16+{0..3}]
#pragma unroll
    for (int it = 0; it < 8; ++it) {
      const int ci = it * 256 + tid;
      const int hh = ci >> 10, T = (ci >> 9) & 1, inner = ci & 511;
      const int ccol = inner & 15, cq = (inner >> 4) & 3;
      const int dt = (inner >> 6) & 3, kh2 = (inner >> 8) & 1;
      const int gmb = m0 + T * 64;
      const int bi = gmb / NSP, ktile = (gmb - bi * NSP) >> 6;
      const bf16* eprow =
          ep + (hh * 64 + dt * 16 + ccol) * 132 + T * 64 + kh2 * 32 + cq * 4;
      short8 v;
      ((bfx4*)&v)[0] = *(const bfx4*)(eprow);
      ((bfx4*)&v)[1] = *(const bfx4*)(eprow + 16);
      *(short8*)(kt2_ws +
          (((size_t)(bi * 8 + h0 + hh) * 25 + ktile) * 512 + inner) * 8) = v;
    }
  }
}

// ---------------------------------------------------------------------------
// attn: R10 verbatim. LDS-free K-loop (4 waves: qg=wave&1 32 qcols,
// kh=wave>>1 32 keys), XCD-swizzled flat grid (800), register double-buffer,
// launch_bounds(256,2). Best measured: ~44.5us.
// ---------------------------------------------------------------------------

#define LOADF(KF, KTF, KT)                                                    \
  {                                                                           \
    const bf16* kc_  = k2b  + (KT) * 4096;                                    \
    const bf16* kc2_ = kt2b + (KT) * 4096;                                    \
    _Pragma("unroll")                                                         \
    for (int ti = 0; ti < 2; ++ti)                                            \
      _Pragma("unroll")                                                       \
      for (int f = 0; f < 2; ++f)                                             \
        KF[ti][f] =                                                           \
            *(const short8*)(kc_ + (((kh * 2 + ti) * 2 + f) * 64 + lane) * 8);\
    _Pragma("unroll")                                                         \
    for (int dt = 0; dt < 4; ++dt)                                            \
      KTF[dt] = *(const short8*)(kc2_ + ((kh * 4 + dt) * 64 + lane) * 8);     \
  }

#define COMPUTEF(KF, KTF)                                                     \
  {                                                                           \
    f32x4 s[2][2];                                                            \
    _Pragma("unroll")                                                         \
    for (int ti = 0; ti < 2; ++ti)                                            \
      _Pragma("unroll")                                                       \
      for (int ct = 0; ct < 2; ++ct) {                                        \
        f32x4 t = {0.f, 0.f, 0.f, 0.f};                                       \
        t = mfma32(KF[ti][0], qb[ct][0], t);                                  \
        t = mfma32(KF[ti][1], qb[ct][1], t);                                  \
        s[ti][ct] = t;                                                        \
      }                                                                       \
    bfx4 p4[2][2];                                                            \
    _Pragma("unroll")                                                         \
    for (int ti = 0; ti < 2; ++ti)                                            \
      _Pragma("unroll")                                                       \
      for (int ct = 0; ct < 2; ++ct) {                                        \
        _Pragma("unroll")                                                     \
        for (int r = 0; r < 4; ++r) s[ti][ct][r] = __expf(s[ti][ct][r]);      \
        l_part[ct] +=                                                         \
            s[ti][ct][0] + s[ti][ct][1] + s[ti][ct][2] + s[ti][ct][3];        \
        bf16* pp = (bf16*)&p4[ti][ct];                                        \
        _Pragma("unroll")                                                     \
        for (int r = 0; r < 4; ++r) pp[r] = __float2bfloat16(s[ti][ct][r]);   \
      }                                                                       \
    _Pragma("unroll")                                                         \
    for (int dt = 0; dt < 4; ++dt) {                                          \
      bfx4 alo = __builtin_shufflevector(KTF[dt], KTF[dt], 0, 1, 2, 3);       \
      bfx4 ahi = __builtin_shufflevector(KTF[dt], KTF[dt], 4, 5, 6, 7);       \
      _Pragma("unroll")                                                       \
      for (int ct = 0; ct < 2; ++ct) {                                        \
        oacc[dt][ct] = mfma_k16(alo, p4[0][ct], oacc[dt][ct]);                \
        oacc[dt][ct] = mfma_k16(ahi, p4[1][ct], oacc[dt][ct]);                \
      }                                                                       \
    }                                                                         \
  }

extern "C" __global__ __launch_bounds__(256, 2)
void attn_kernel(const bf16* __restrict__ q_ws, const bf16* __restrict__ k2_ws,
                 const bf16* __restrict__ kt2_ws, float* __restrict__ out)
{
  __shared__ float red[2][64][36];

  // XCD swizzle: flat id; id%8 selects XCD (round-robin heuristic) == bh%8,
  // so all 25 qt-blocks of a bh share one XCD's L2. Bijective on 0..799.
  const int id = blockIdx.x;
  const int xr = id & 7, inner = id >> 3;      // inner 0..99
  const int qt = inner % 25;
  const int bh = (inner / 25) * 8 + xr;        // 0..31
  const int b = bh >> 3, h = bh & 7;
  const int tid  = threadIdx.x;
  const int wave = tid >> 6;
  const int lane = tid & 63;
  const int col  = lane & 15;
  const int quad = lane >> 4;
  const int qg = wave & 1, kh = wave >> 1;

  // loop-invariant Q B-fragments (natural layout, one-time strided gather)
  short8 qb[2][2];
#pragma unroll
  for (int ct = 0; ct < 2; ++ct) {
    const bf16* qp =
        q_ws + ((size_t)bh * NSP + qt * 64 + (qg * 2 + ct) * 16 + col) * 64;
    qb[ct][0] = *(const short8*)(qp + quad * 8);
    qb[ct][1] = *(const short8*)(qp + 32 + quad * 8);
  }

  f32x4 oacc[4][2];
#pragma unroll
  for (int i = 0; i < 4; ++i)
#pragma unroll
    for (int j = 0; j < 2; ++j) oacc[i][j] = {0.f, 0.f, 0.f, 0.f};
  float l_part[2] = {0.f, 0.f};

  const bf16* k2b  = k2_ws  + (size_t)bh * 25 * 4096;
  const bf16* kt2b = kt2_ws + (size_t)bh * 25 * 4096;

  // register double-buffer: prefetch kt+1 while computing kt
  short8 kfA[2][2], ktfA[4], kfB[2][2], ktfB[4];
  LOADF(kfA, ktfA, 0)
#pragma unroll 1
  for (int i = 0; i < 12; ++i) {
    LOADF(kfB, ktfB, 2 * i + 1)
    COMPUTEF(kfA, ktfA)
    LOADF(kfA, ktfA, 2 * i + 2)
    COMPUTEF(kfB, ktfB)
  }
  COMPUTEF(kfA, ktfA)

  // reduce l over quads (this wave's 32 keys)
#pragma unroll
  for (int ct = 0; ct < 2; ++ct) {
    l_part[ct] += __shfl_xor(l_part[ct], 16, 64);
    l_part[ct] += __shfl_xor(l_part[ct], 32, 64);
  }

  // cross-wave (kh) reduce via LDS
  if (wave >= 2) {
    float* dst = &red[wave - 2][lane][0];
#pragma unroll
    for (int dt = 0; dt < 4; ++dt)
#pragma unroll
      for (int ct = 0; ct < 2; ++ct)
        *(f32x4*)(dst + (dt * 2 + ct) * 4) = oacc[dt][ct];
    dst[32] = l_part[0]; dst[33] = l_part[1];
  }
  __syncthreads();
  if (wave < 2) {
    const float* srcr = &red[wave][lane][0];
#pragma unroll
    for (int dt = 0; dt < 4; ++dt)
#pragma unroll
      for (int ct = 0; ct < 2; ++ct)
        oacc[dt][ct] += *(const f32x4*)(srcr + (dt * 2 + ct) * 4);
    const float inv0 = 1.f / (l_part[0] + srcr[32]);
    const float inv1 = 1.f / (l_part[1] + srcr[33]);
#pragma unroll
    for (int ct = 0; ct < 2; ++ct) {
      const float inv = ct ? inv1 : inv0;
      const int qrow = qt * 64 + (qg * 2 + ct) * 16 + col;
      float* ob = out + ((size_t)b * NSP + qrow) * CDIM + h * 64;
#pragma unroll
      for (int dt = 0; dt < 4; ++dt) {
        float4 v;
        v.x = oacc[dt][ct][0] * inv; v.y = oacc[dt][ct][1] * inv;
        v.z = oacc[dt][ct][2] * inv; v.w = oacc[dt][ct][3] * inv;
        *(float4*)(ob + dt * 16 + quad * 4) = v;
      }
    }
  }
}

extern "C" void kernel_launch(void* const* d_in, const int* in_sizes, int n_in,
                              void* d_out, int out_size, void* d_ws, size_t ws_size,
                              hipStream_t stream) {
  const float* x     = (const float*)d_in[0];
  const float* sin_t = (const float*)d_in[1];
  const float* cos_t = (const float*)d_in[2];
  const float* w_qkv = (const float*)d_in[3];
  const float* b_qkv = (const float*)d_in[4];
  float* out = (float*)d_out;

  const size_t QK = (size_t)32 * NSP * DH;
  bf16* q_ws   = (bf16*)d_ws;
  bf16* k2_ws  = q_ws + QK;
  bf16* kt2_ws = k2_ws + QK;
  bf16* x_bf   = kt2_ws + QK;
  bf16* w_bf   = x_bf + (size_t)6400 * CDIM;
  float* sinT  = (float*)(w_bf + (size_t)1024 * CDIM);
  float* cosT  = sinT + (size_t)DH * NSP;

  cvt_kernel<<<1906, 256, 0, stream>>>(x, w_qkv, sin_t, cos_t, x_bf, w_bf, sinT, cosT);

  dim3 gproj(50, 8);
  proj_kernel<<<gproj, 256, 0, stream>>>(x_bf, w_bf, b_qkv, sinT, cosT,
                                         q_ws, k2_ws, kt2_ws);

  attn_kernel<<<800, 256, 0, stream>>>(q_ws, k2_ws, kt2_ws, out);
}

// Round 12
// 130.499 us; speedup vs baseline: 1.2075x; 1.0256x over previous
//
#include <hip/hip_runtime.h>
#include <hip/hip_bf16.h>

// NormalAttention: B=4, N=1600, C=512, heads=8, dh=64. out = softmax(qk^T/8)@k.
// R17: R16 (best, 133.8us) + 2-phase prefetch in proj's K-loop (T3-minimum).
// R16's loop was STAGE -> barrier -> compute -> barrier: the first barrier
// exposes the full staging latency and there are 2 barriers/kt. Now: LDS
// double-buffer (2 x 32KB, ep overlays), per iter issue STAGE(kt+1) BEFORE
// compute(kt), ONE __syncthreads per iter (its implicit vmcnt drain lands the
// stage that had the whole compute phase in flight). Hazards: stage at t
// writes buf[(t+1)&1], last read in iter t-1, protected by t-1's barrier;
// ep overlay written only after the final barrier. Staging swizzle + read
// XOR identical to R16 (bit-exact, verified by R16's absmax).
// cvt: R5 verbatim. attn: R10 verbatim (44.5us, saturated).

typedef __hip_bfloat16 bf16;
typedef __attribute__((ext_vector_type(8))) short short8;
typedef __attribute__((ext_vector_type(4))) short bfx4;
typedef __attribute__((ext_vector_type(4))) float f32x4;

#define NSP 1600
#define CDIM 512
#define DH 64

#define GLD16(g, l)                                                           \
  __builtin_amdgcn_global_load_lds(                                           \
      (const __attribute__((address_space(1))) unsigned int*)(g),             \
      (__attribute__((address_space(3))) unsigned int*)(l), 16, 0, 0)

__device__ __forceinline__ f32x4 mfma32(short8 a, short8 b, f32x4 c) {
  return __builtin_amdgcn_mfma_f32_16x16x32_bf16(a, b, c, 0, 0, 0);
}

#if __has_builtin(__builtin_amdgcn_mfma_f32_16x16x16bf16_1k)
__device__ __forceinline__ f32x4 mfma_k16(bfx4 a, bfx4 b, f32x4 c) {
  return __builtin_amdgcn_mfma_f32_16x16x16bf16_1k(a, b, c, 0, 0, 0);
}
#else
__device__ __forceinline__ f32x4 mfma_k16(bfx4 a, bfx4 b, f32x4 c) {
  short8 a8 = {a.x, a.y, a.z, a.w, 0, 0, 0, 0};
  short8 b8 = {b.x, b.y, b.z, b.w, 0, 0, 0, 0};
  return __builtin_amdgcn_mfma_f32_16x16x32_bf16(a8, b8, c, 0, 0, 0);
}
#endif

__device__ __forceinline__ short8 cvt8(float4 v0, float4 v1) {
  short8 r; bf16* p = (bf16*)&r;
  p[0] = __float2bfloat16(v0.x); p[1] = __float2bfloat16(v0.y);
  p[2] = __float2bfloat16(v0.z); p[3] = __float2bfloat16(v0.w);
  p[4] = __float2bfloat16(v1.x); p[5] = __float2bfloat16(v1.y);
  p[6] = __float2bfloat16(v1.z); p[7] = __float2bfloat16(v1.w);
  return r;
}

// ---------------------------------------------------------------------------
// cvt: x,w -> bf16 (plain); sin/cos -> (d,n) fp32 transpose.  (R5 verbatim)
// ---------------------------------------------------------------------------
extern "C" __global__ __launch_bounds__(256)
void cvt_kernel(const float* __restrict__ x, const float* __restrict__ w,
                const float* __restrict__ sin_t, const float* __restrict__ cos_t,
                bf16* __restrict__ x_bf, bf16* __restrict__ w_bf,
                float* __restrict__ sinT, float* __restrict__ cosT)
{
  __shared__ float t_lds[64][68];
  const int bid = blockIdx.x, tid = threadIdx.x;
  if (bid < 1600) {
    const size_t i = (size_t)bid * 2048 + tid * 8;
    float4 v0 = *(const float4*)(x + i);
    float4 v1 = *(const float4*)(x + i + 4);
    *(short8*)(x_bf + i) = cvt8(v0, v1);
  } else if (bid < 1856) {
    const size_t i = (size_t)(bid - 1600) * 2048 + tid * 8;
    float4 v0 = *(const float4*)(w + i);
    float4 v1 = *(const float4*)(w + i + 4);
    *(short8*)(w_bf + i) = cvt8(v0, v1);
  } else {
    const int t = bid - 1856;
    const float* src = (t < 25) ? sin_t : cos_t;
    float* dst = (t < 25) ? sinT : cosT;
    const int nt = (t < 25) ? t : t - 25;
    const int r = tid >> 2, c = (tid & 3) * 16;
#pragma unroll
    for (int j = 0; j < 4; ++j)
      *(float4*)&t_lds[r][c + j * 4] =
          *(const float4*)(src + (size_t)(nt * 64 + r) * 64 + c + j * 4);
    __syncthreads();
#pragma unroll
    for (int j4 = 0; j4 < 4; ++j4) {
      float4 o;
      o.x = t_lds[c + j4 * 4 + 0][r];
      o.y = t_lds[c + j4 * 4 + 1][r];
      o.z = t_lds[c + j4 * 4 + 2][r];
      o.w = t_lds[c + j4 * 4 + 3][r];
      *(float4*)(dst + (size_t)r * NSP + nt * 64 + c + j4 * 4) = o;
    }
  }
}

// ---------------------------------------------------------------------------
// proj: 128x128 tile, BK=64, grid (50,8). global_load_lds w=16 staging into
// DOUBLE-buffered LDS [2][128][64]; per iter: issue STAGE(kt+1) -> compute
// from buf[kt&1] -> one __syncthreads. Read-side XOR swizzle = R16 verbatim.
// Epilogue R5/R7 verbatim (ep overlays buf space after final barrier).
// ---------------------------------------------------------------------------
extern "C" __global__ __launch_bounds__(256)
void proj_kernel(const bf16* __restrict__ x_bf, const bf16* __restrict__ w_bf,
                 const float* __restrict__ bias, const float* __restrict__ sinT,
                 const float* __restrict__ cosT, bf16* __restrict__ q_ws,
                 bf16* __restrict__ k2_ws, bf16* __restrict__ kt2_ws)
{
  __shared__ __align__(16) char smem[65536];   // buf0: x16K|w16K, buf1: same
  bf16* ep = (bf16*)smem;                      // [128][132] epilogue overlay

  const int tid  = threadIdx.x;
  const int wave = tid >> 6;
  const int lane = tid & 63;
  const int col  = lane & 15;
  const int quad = lane >> 4;
  const int wm = wave >> 1, wo = wave & 1;
  const int m0 = blockIdx.x * 128;
  const int o0 = blockIdx.y * 128;

  f32x4 acc[4][4];
#pragma unroll
  for (int i = 0; i < 4; ++i)
#pragma unroll
    for (int j = 0; j < 4; ++j) acc[i][j] = {0.f, 0.f, 0.f, 0.f};

  // staging geometry (R16-verified): per wave 4 instrs x (x,w); instr i covers
  // rows wave*32+i*8 .. +7; lane l -> row l>>3, source chunk (l&7)^(l>>3).
  const int rl = lane >> 3;
  const int sck = (lane & 7) ^ rl;
  const int c7 = col & 7;

#define STAGEP(B, KT)                                                         \
  {                                                                           \
    char* xd = smem + (B) * 32768 + wave * 4096;                              \
    char* wd = smem + (B) * 32768 + 16384 + wave * 4096;                      \
    _Pragma("unroll")                                                         \
    for (int i = 0; i < 4; ++i) {                                             \
      const int row = wave * 32 + i * 8 + rl;                                 \
      GLD16(x_bf + ((size_t)(m0 + row) << 9) + (KT) * 64 + sck * 8,           \
            xd + i * 1024);                                                   \
      GLD16(w_bf + ((size_t)(o0 + row) << 9) + (KT) * 64 + sck * 8,           \
            wd + i * 1024);                                                   \
    }                                                                         \
  }

  STAGEP(0, 0)
  __syncthreads();   // buf0 ready

#pragma unroll
  for (int kt = 0; kt < 8; ++kt) {
    if (kt < 7) { STAGEP((kt + 1) & 1, kt + 1) }   // in flight under compute
    const char* xls = smem + (kt & 1) * 32768;
    const char* wls = xls + 16384;
#pragma unroll
    for (int half = 0; half < 2; ++half) {
      short8 af[4], bfr[4];
#pragma unroll
      for (int mt = 0; mt < 4; ++mt) {
        const int r = wm * 64 + mt * 16 + col;
        af[mt] = *(const short8*)(xls + r * 128 + (((half * 4 + quad) ^ c7) << 4));
      }
#pragma unroll
      for (int ot = 0; ot < 4; ++ot) {
        const int r = wo * 64 + ot * 16 + col;
        bfr[ot] = *(const short8*)(wls + r * 128 + (((half * 4 + quad) ^ c7) << 4));
      }
#pragma unroll
      for (int mt = 0; mt < 4; ++mt)
#pragma unroll
        for (int ot = 0; ot < 4; ++ot)
          acc[mt][ot] = mfma32(af[mt], bfr[ot], acc[mt][ot]);
    }
    __syncthreads();   // one barrier/iter: drains stage, protects buf reuse
  }

  // ---- epilogue stage 1: theta_shift -> ep[o_local][m_local] (bf16) ----
  const int b_idx = (m0 + wm * 64) / NSP;
  const int n0w   = m0 + wm * 64 - b_idx * NSP;
  const bool isq  = (o0 < 512);
#pragma unroll
  for (int ot = 0; ot < 4; ++ot) {
    const int o_local = wo * 64 + ot * 16 + col;
    const int o_g = o0 + o_local;
    const float bv = bias[o_g];
    const int d = o_g & 63;
#pragma unroll
    for (int mt = 0; mt < 4; ++mt) {
      const int nl = mt * 16 + quad * 4;
      float t[4], rot[4];
#pragma unroll
      for (int r = 0; r < 4; ++r) t[r] = acc[mt][ot][r] + bv;
#pragma unroll
      for (int r = 0; r < 4; ++r) {
        float tp = __shfl_xor(t[r], 1, 64);
        rot[r] = (lane & 1) ? tp : -tp;
      }
      const float4 c4 = *(const float4*)(cosT + (size_t)d * NSP + n0w + nl);
      const float4 s4 = *(const float4*)(sinT + (size_t)d * NSP + n0w + nl);
      float res[4];
      res[0] = t[0] * c4.x + rot[0] * s4.x;
      res[1] = t[1] * c4.y + rot[1] * s4.y;
      res[2] = t[2] * c4.z + rot[2] * s4.z;
      res[3] = t[3] * c4.w + rot[3] * s4.w;
      if (isq) {
#pragma unroll
        for (int r = 0; r < 4; ++r) res[r] *= 0.125f;
      }
      bfx4 pk; bf16* pp = (bf16*)&pk;
#pragma unroll
      for (int r = 0; r < 4; ++r) pp[r] = __float2bfloat16(res[r]);
      *(bfx4*)&ep[o_local * 132 + wm * 64 + nl] = pk;
    }
  }
  __syncthreads();

  // ---- epilogue stage 2: coalesced global stores (R5/R7 verbatim) ----
  if (isq) {   // q_ws (bh,n,d) natural
    const int m_l = tid >> 1, half = tid & 1;
    const int gm = m0 + m_l;
    const int bi = gm / NSP, n = gm - bi * NSP;
    const int h = (o0 >> 6) + half;
    bf16* base = q_ws + ((size_t)(bi * 8 + h) * NSP + n) * 64;
#pragma unroll
    for (int c = 0; c < 8; ++c) {
      short8 v; bf16* vp = (bf16*)&v;
#pragma unroll
      for (int j = 0; j < 8; ++j) vp[j] = ep[(half * 64 + c * 8 + j) * 132 + m_l];
      *(short8*)(base + c * 8) = v;
    }
  } else {
    const int h0 = (o0 - 512) >> 6;   // 0,2,4,6 ; heads h0, h0+1
    // k2_ws: per (bh,ktile) 512 chunks [kh][ti][f][quad][col];
    // chunk = K[key=(2kh+ti)*16+col][d = (f*4+quad)*8 .. +8]
#pragma unroll
    for (int it = 0; it < 8; ++it) {
      const int ci = it * 256 + tid;              // 0..2047
      const int hh = ci >> 10, T = (ci >> 9) & 1, inner = ci & 511;
      const int ccol = inner & 15, cq = (inner >> 4) & 3;
      const int f = (inner >> 6) & 1, ti = (inner >> 7) & 1, kh2 = (inner >> 8) & 1;
      const int gmb = m0 + T * 64;
      const int bi = gmb / NSP, ktile = (gmb - bi * NSP) >> 6;
      const int m_l = T * 64 + (2 * kh2 + ti) * 16 + ccol;
      const int er0 = hh * 64 + (f * 4 + cq) * 8;
      short8 v; bf16* vp = (bf16*)&v;
#pragma unroll
      for (int j = 0; j < 8; ++j) vp[j] = ep[(er0 + j) * 132 + m_l];
      *(short8*)(k2_ws +
          (((size_t)(bi * 8 + h0 + hh) * 25 + ktile) * 512 + inner) * 8) = v;
    }
    // kt2_ws: per (bh,ktile) 512 chunks [kh][dt][quad][col];
    // chunk = kT[d=dt*16+col][packed keys kh*32+quad*4+{0..3}, +16+{0..3}]
#pragma unroll
    for (int it = 0; it < 8; ++it) {
      const int ci = it * 256 + tid;
      const int hh = ci >> 10, T = (ci >> 9) & 1, inner = ci & 511;
      const int ccol = inner & 15, cq = (inner >> 4) & 3;
      const int dt = (inner >> 6) & 3, kh2 = (inner >> 8) & 1;
      const int gmb = m0 + T * 64;
      const int bi = gmb / NSP, ktile = (gmb - bi * NSP) >> 6;
      const bf16* eprow =
          ep + (hh * 64 + dt * 16 + ccol) * 132 + T * 64 + kh2 * 32 + cq * 4;
      short8 v;
      ((bfx4*)&v)[0] = *(const bfx4*)(eprow);
      ((bfx4*)&v)[1] = *(const bfx4*)(eprow + 16);
      *(short8*)(kt2_ws +
          (((size_t)(bi * 8 + h0 + hh) * 25 + ktile) * 512 + inner) * 8) = v;
    }
  }
}

// ---------------------------------------------------------------------------
// attn: R10 verbatim. LDS-free K-loop (4 waves: qg=wave&1 32 qcols,
// kh=wave>>1 32 keys), XCD-swizzled flat grid (800), register double-buffer,
// launch_bounds(256,2). Best measured: ~44.5us.
// ---------------------------------------------------------------------------

#define LOADF(KF, KTF, KT)                                                    \
  {                                                                           \
    const bf16* kc_  = k2b  + (KT) * 4096;                                    \
    const bf16* kc2_ = kt2b + (KT) * 4096;                                    \
    _Pragma("unroll")                                                         \
    for (int ti = 0; ti < 2; ++ti)                                            \
      _Pragma("unroll")                                                       \
      for (int f = 0; f < 2; ++f)                                             \
        KF[ti][f] =                                                           \
            *(const short8*)(kc_ + (((kh * 2 + ti) * 2 + f) * 64 + lane) * 8);\
    _Pragma("unroll")                                                         \
    for (int dt = 0; dt < 4; ++dt)                                            \
      KTF[dt] = *(const short8*)(kc2_ + ((kh * 4 + dt) * 64 + lane) * 8);     \
  }

#define COMPUTEF(KF, KTF)                                                     \
  {                                                                           \
    f32x4 s[2][2];                                                            \
    _Pragma("unroll")                                                         \
    for (int ti = 0; ti < 2; ++ti)                                            \
      _Pragma("unroll")                                                       \
      for (int ct = 0; ct < 2; ++ct) {                                        \
        f32x4 t = {0.f, 0.f, 0.f, 0.f};                                       \
        t = mfma32(KF[ti][0], qb[ct][0], t);                                  \
        t = mfma32(KF[ti][1], qb[ct][1], t);                                  \
        s[ti][ct] = t;                                                        \
      }                                                                       \
    bfx4 p4[2][2];                                                            \
    _Pragma("unroll")                                                         \
    for (int ti = 0; ti < 2; ++ti)                                            \
      _Pragma("unroll")                                                       \
      for (int ct = 0; ct < 2; ++ct) {                                        \
        _Pragma("unroll")                                                     \
        for (int r = 0; r < 4; ++r) s[ti][ct][r] = __expf(s[ti][ct][r]);      \
        l_part[ct] +=                                                         \
            s[ti][ct][0] + s[ti][ct][1] + s[ti][ct][2] + s[ti][ct][3];        \
        bf16* pp = (bf16*)&p4[ti][ct];                                        \
        _Pragma("unroll")                                                     \
        for (int r = 0; r < 4; ++r) pp[r] = __float2bfloat16(s[ti][ct][r]);   \
      }                                                                       \
    _Pragma("unroll")                                                         \
    for (int dt = 0; dt < 4; ++dt) {                                          \
      bfx4 alo = __builtin_shufflevector(KTF[dt], KTF[dt], 0, 1, 2, 3);       \
      bfx4 ahi = __builtin_shufflevector(KTF[dt], KTF[dt], 4, 5, 6, 7);       \
      _Pragma("unroll")                                                       \
      for (int ct = 0; ct < 2; ++ct) {                                        \
        oacc[dt][ct] = mfma_k16(alo, p4[0][ct], oacc[dt][ct]);                \
        oacc[dt][ct] = mfma_k16(ahi, p4[1][ct], oacc[dt][ct]);                \
      }                                                                       \
    }                                                                         \
  }

extern "C" __global__ __launch_bounds__(256, 2)
void attn_kernel(const bf16* __restrict__ q_ws, const bf16* __restrict__ k2_ws,
                 const bf16* __restrict__ kt2_ws, float* __restrict__ out)
{
  __shared__ float red[2][64][36];

  // XCD swizzle: flat id; id%8 selects XCD (round-robin heuristic) == bh%8,
  // so all 25 qt-blocks of a bh share one XCD's L2. Bijective on 0..799.
  const int id = blockIdx.x;
  const int xr = id & 7, inner = id >> 3;      // inner 0..99
  const int qt = inner % 25;
  const int bh = (inner / 25) * 8 + xr;        // 0..31
  const int b = bh >> 3, h = bh & 7;
  const int tid  = threadIdx.x;
  const int wave = tid >> 6;
  const int lane = tid & 63;
  const int col  = lane & 15;
  const int quad = lane >> 4;
  const int qg = wave & 1, kh = wave >> 1;

  // loop-invariant Q B-fragments (natural layout, one-time strided gather)
  short8 qb[2][2];
#pragma unroll
  for (int ct = 0; ct < 2; ++ct) {
    const bf16* qp =
        q_ws + ((size_t)bh * NSP + qt * 64 + (qg * 2 + ct) * 16 + col) * 64;
    qb[ct][0] = *(const short8*)(qp + quad * 8);
    qb[ct][1] = *(const short8*)(qp + 32 + quad * 8);
  }

  f32x4 oacc[4][2];
#pragma unroll
  for (int i = 0; i < 4; ++i)
#pragma unroll
    for (int j = 0; j < 2; ++j) oacc[i][j] = {0.f, 0.f, 0.f, 0.f};
  float l_part[2] = {0.f, 0.f};

  const bf16* k2b  = k2_ws  + (size_t)bh * 25 * 4096;
  const bf16* kt2b = kt2_ws + (size_t)bh * 25 * 4096;

  // register double-buffer: prefetch kt+1 while computing kt
  short8 kfA[2][2], ktfA[4], kfB[2][2], ktfB[4];
  LOADF(kfA, ktfA, 0)
#pragma unroll 1
  for (int i = 0; i < 12; ++i) {
    LOADF(kfB, ktfB, 2 * i + 1)
    COMPUTEF(kfA, ktfA)
    LOADF(kfA, ktfA, 2 * i + 2)
    COMPUTEF(kfB, ktfB)
  }
  COMPUTEF(kfA, ktfA)

  // reduce l over quads (this wave's 32 keys)
#pragma unroll
  for (int ct = 0; ct < 2; ++ct) {
    l_part[ct] += __shfl_xor(l_part[ct], 16, 64);
    l_part[ct] += __shfl_xor(l_part[ct], 32, 64);
  }

  // cross-wave (kh) reduce via LDS
  if (wave >= 2) {
    float* dst = &red[wave - 2][lane][0];
#pragma unroll
    for (int dt = 0; dt < 4; ++dt)
#pragma unroll
      for (int ct = 0; ct < 2; ++ct)
        *(f32x4*)(dst + (dt * 2 + ct) * 4) = oacc[dt][ct];
    dst[32] = l_part[0]; dst[33] = l_part[1];
  }
  __syncthreads();
  if (wave < 2) {
    const float* srcr = &red[wave][lane][0];
#pragma unroll
    for (int dt = 0; dt < 4; ++dt)
#pragma unroll
      for (int ct = 0; ct < 2; ++ct)
        oacc[dt][ct] += *(const f32x4*)(srcr + (dt * 2 + ct) * 4);
    const float inv0 = 1.f / (l_part[0] + srcr[32]);
    const float inv1 = 1.f / (l_part[1] + srcr[33]);
#pragma unroll
    for (int ct = 0; ct < 2; ++ct) {
      const float inv = ct ? inv1 : inv0;
      const int qrow = qt * 64 + (qg * 2 + ct) * 16 + col;
      float* ob = out + ((size_t)b * NSP + qrow) * CDIM + h * 64;
#pragma unroll
      for (int dt = 0; dt < 4; ++dt) {
        float4 v;
        v.x = oacc[dt][ct][0] * inv; v.y = oacc[dt][ct][1] * inv;
        v.z = oacc[dt][ct][2] * inv; v.w = oacc[dt][ct][3] * inv;
        *(float4*)(ob + dt * 16 + quad * 4) = v;
      }
    }
  }
}

extern "C" void kernel_launch(void* const* d_in, const int* in_sizes, int n_in,
                              void* d_out, int out_size, void* d_ws, size_t ws_size,
                              hipStream_t stream) {
  const float* x     = (const float*)d_in[0];
  const float* sin_t = (const float*)d_in[1];
  const float* cos_t = (const float*)d_in[2];
  const float* w_qkv = (const float*)d_in[3];
  const float* b_qkv = (const float*)d_in[4];
  float* out = (float*)d_out;

  const size_t QK = (size_t)32 * NSP * DH;
  bf16* q_ws   = (bf16*)d_ws;
  bf16* k2_ws  = q_ws + QK;
  bf16* kt2_ws = k2_ws + QK;
  bf16* x_bf   = kt2_ws + QK;
  bf16* w_bf   = x_bf + (size_t)6400 * CDIM;
  float* sinT  = (float*)(w_bf + (size_t)1024 * CDIM);
  float* cosT  = sinT + (size_t)DH * NSP;

  cvt_kernel<<<1906, 256, 0, stream>>>(x, w_qkv, sin_t, cos_t, x_bf, w_bf, sinT, cosT);

  dim3 gproj(50, 8);
  proj_kernel<<<gproj, 256, 0, stream>>>(x_bf, w_bf, b_qkv, sinT, cosT,
                                         q_ws, k2_ws, kt2_ws);

  attn_kernel<<<800, 256, 0, stream>>>(q_ws, k2_ws, kt2_ws, out);
}